// Round 7
// baseline (210.177 us; speedup 1.0000x reference)
//
#include <hip/hip_runtime.h>
#include <hip/hip_bf16.h>
#include <stdint.h>

#define HID 2048
#define NH  32
#define HD  64
#define NB  8
#define NS  16
#define PAST 4096

// log2(e) / sqrt(D) = 1.4426950408889634 / 8
#define QSCALE 0.18033688011112042591f

typedef __attribute__((ext_vector_type(8))) short short8;
typedef __attribute__((ext_vector_type(4))) short short4v;
typedef __attribute__((ext_vector_type(4))) float f32x4;

#define MFMA(a, b, c) __builtin_amdgcn_mfma_f32_16x16x32_bf16((a), (b), (c), 0, 0, 0)

#define PART_STRIDE 1088  // 16 m + 16 l + 16*64 O + pad, floats
#define NSPLIT 4          // attn splits per (b,h); 1024 pos per split
#define VSLAB  8704       // bytes per wave: 64 x 68 u16 (padded V tile)

static __device__ __forceinline__ short f2bf(float f) {
    __hip_bfloat16 h = __float2bfloat16(f);
    return *reinterpret_cast<short*>(&h);
}

static __device__ __forceinline__ short8 pack8(float4 a, float4 b) {
    short8 r;
    r[0] = f2bf(a.x); r[1] = f2bf(a.y); r[2] = f2bf(a.z); r[3] = f2bf(a.w);
    r[4] = f2bf(b.x); r[5] = f2bf(b.y); r[6] = f2bf(b.z); r[7] = f2bf(b.w);
    return r;
}

static __device__ __forceinline__ short4v pack4(float4 a) {
    short4v r;
    r[0] = f2bf(a.x); r[1] = f2bf(a.y); r[2] = f2bf(a.z); r[3] = f2bf(a.w);
    return r;
}

static __device__ __forceinline__ short8 pack8s(float4 a, float4 b, float s) {
    short8 r;
    r[0] = f2bf(a.x * s); r[1] = f2bf(a.y * s); r[2] = f2bf(a.z * s); r[3] = f2bf(a.w * s);
    r[4] = f2bf(b.x * s); r[5] = f2bf(b.y * s); r[6] = f2bf(b.z * s); r[7] = f2bf(b.w * s);
    return r;
}

// ---------------- hidden fp32 -> bf16 ----------------
__global__ __launch_bounds__(256) void cvt_kernel(const float* __restrict__ in,
                                                  short* __restrict__ out) {
    int i = (blockIdx.x * 256 + threadIdx.x) * 4;
    float4 v = *reinterpret_cast<const float4*>(in + i);
    short4v o;
    o[0] = f2bf(v.x); o[1] = f2bf(v.y); o[2] = f2bf(v.z); o[3] = f2bf(v.w);
    *reinterpret_cast<short4v*>(out + i) = o;
}

// ------- Y += Xbf16 @ W^T  (M=128, K-split x4, N=16 per block), atomic -----
__global__ __launch_bounds__(128) void proj_kernel(
        const short* __restrict__ X,
        const float* __restrict__ W0, const float* __restrict__ W1,
        const float* __restrict__ W2,
        float* __restrict__ Y0, float* __restrict__ Y1, float* __restrict__ Y2) {
    int mat   = blockIdx.x >> 9;
    int rest  = blockIdx.x & 511;
    int strip = rest >> 2, ks = rest & 3;
    int nbase = strip * 16;
    int k0    = ks * 512;
    const float* W = (mat == 0) ? W0 : (mat == 1) ? W1 : W2;
    float*       Y = (mat == 0) ? Y0 : (mat == 1) ? Y1 : Y2;

    int lane = threadIdx.x & 63;
    int wave = threadIdx.x >> 6;
    int lr = lane & 15, g = lane >> 4;

    f32x4 acc0 = {0.f, 0.f, 0.f, 0.f};
    f32x4 acc1 = {0.f, 0.f, 0.f, 0.f};
    f32x4 acc2 = {0.f, 0.f, 0.f, 0.f};
    f32x4 acc3 = {0.f, 0.f, 0.f, 0.f};

    const short* xr = X + (size_t)(wave * 64 + lr) * HID + g * 8 + k0;
    const float* wr = W + (size_t)(nbase + lr) * HID + g * 8 + k0;

    #pragma unroll 4
    for (int kc = 0; kc < 512; kc += 32) {
        float4 w0 = *reinterpret_cast<const float4*>(wr + kc);
        float4 w1 = *reinterpret_cast<const float4*>(wr + kc + 4);
        short8 bb = pack8(w0, w1);
        short8 a0 = *reinterpret_cast<const short8*>(xr + kc);
        short8 a1 = *reinterpret_cast<const short8*>(xr + (size_t)16 * HID + kc);
        short8 a2 = *reinterpret_cast<const short8*>(xr + (size_t)32 * HID + kc);
        short8 a3 = *reinterpret_cast<const short8*>(xr + (size_t)48 * HID + kc);
        acc0 = MFMA(a0, bb, acc0);
        acc1 = MFMA(a1, bb, acc1);
        acc2 = MFMA(a2, bb, acc2);
        acc3 = MFMA(a3, bb, acc3);
    }
    #define STACC(accv, f) do { \
        atomicAdd(&Y[(size_t)(wave * 64 + (f) * 16 + (g << 2) + 0) * HID + nbase + lr], accv[0]); \
        atomicAdd(&Y[(size_t)(wave * 64 + (f) * 16 + (g << 2) + 1) * HID + nbase + lr], accv[1]); \
        atomicAdd(&Y[(size_t)(wave * 64 + (f) * 16 + (g << 2) + 2) * HID + nbase + lr], accv[2]); \
        atomicAdd(&Y[(size_t)(wave * 64 + (f) * 16 + (g << 2) + 3) * HID + nbase + lr], accv[3]); \
    } while (0)
    STACC(acc0, 0); STACC(acc1, 1); STACC(acc2, 2); STACC(acc3, 3);
    #undef STACC
}

// ---------------- fused attention, 4 blocks per (b,h) -------------------
// blockIdx.x = bh*4 + split. 256 threads = 4 waves; wave w owns pos
// [split*1024 + w*256, +256) = 4 tiles of 64.
// V path: coalesced float4 -> bf16 -> per-wave LDS slab [64][68] -> u16 frag reads.
__global__ __launch_bounds__(256, 4) void attn_kernel(
        const float* __restrict__ q,
        const float* __restrict__ knew, const float* __restrict__ vnew,
        const float* __restrict__ pastK, const float* __restrict__ pastV,
        float* __restrict__ parts) {
    __shared__ __align__(16) unsigned char lds_raw[4 * VSLAB];
    __shared__ float s_m[4][16];
    __shared__ float s_l[4][16];

    int bid = blockIdx.x;
    int bh = bid >> 2, split = bid & 3;
    int b = bh >> 5, h = bh & 31;
    int wave = threadIdx.x >> 6, lane = threadIdx.x & 63;
    int lq = lane & 15, g = lane >> 4;

    unsigned short* vsl = (unsigned short*)(lds_raw + wave * VSLAB);

    // Q fragments (B operand of swapped QK^T), pre-scaled by log2(e)/8
    const float* qp = q + (size_t)(b * NS + lq) * HID + h * HD + g * 8;
    short8 qf0, qf1;
    {
        float4 a0 = *reinterpret_cast<const float4*>(qp);
        float4 a1 = *reinterpret_cast<const float4*>(qp + 4);
        float4 a2 = *reinterpret_cast<const float4*>(qp + 32);
        float4 a3 = *reinterpret_cast<const float4*>(qp + 36);
        qf0 = pack8s(a0, a1, QSCALE);
        qf1 = pack8s(a2, a3, QSCALE);
    }

    f32x4 o0 = {0.f, 0.f, 0.f, 0.f};
    f32x4 o1 = {0.f, 0.f, 0.f, 0.f};
    f32x4 o2 = {0.f, 0.f, 0.f, 0.f};
    f32x4 o3 = {0.f, 0.f, 0.f, 0.f};
    float m = -__builtin_inff(), lsum = 0.0f;

    const float* kbase = pastK + (size_t)bh * PAST * HD + (size_t)(split * 1024 + wave * 256) * HD;
    const float* vbase = pastV + (size_t)bh * PAST * HD + (size_t)(split * 1024 + wave * 256) * HD;

    // K row loads for QK sub-tile s2i (4 x float4, coalesced-ish, L1-friendly)
    #define KLD(s2i) \
        const float* kr##s2i = kbase + (size_t)(pb + (s2i) * 16 + lq) * HD + (g << 3); \
        float4 ka##s2i = *reinterpret_cast<const float4*>(kr##s2i); \
        float4 kb##s2i = *reinterpret_cast<const float4*>(kr##s2i + 4); \
        float4 kc##s2i = *reinterpret_cast<const float4*>(kr##s2i + 32); \
        float4 kd##s2i = *reinterpret_cast<const float4*>(kr##s2i + 36);

    #define KMM(scv, s2i) do { \
        short8 af0 = pack8(ka##s2i, kb##s2i); \
        short8 af1 = pack8(kc##s2i, kd##s2i); \
        f32x4 sv = {0.f, 0.f, 0.f, 0.f}; \
        sv = MFMA(af0, qf0, sv); \
        sv = MFMA(af1, qf1, sv); \
        scv = sv; \
    } while (0)

    // V: coalesced float4 load I (covers pos=4I+g, d=4*lq..+3), then LDS store
    #define VLD(I) float4 vld##I = *reinterpret_cast<const float4*>(vt + (I) * 256 + lane * 4);
    #define VST(I) *reinterpret_cast<short4v*>(vsl + (4 * (I) + g) * 68 + lq * 4) = pack4(vld##I);

    // V fragment gather from LDS: pos = kfo + 16*(j>=4) + 4g + (j&3), col dcol
    #define LV(p, d) ((short)vsl[(p) * 68 + (d)])
    #define VFR(dst, kfo, dcol) do { \
        dst[0] = LV((kfo) + (g << 2) + 0, (dcol)); \
        dst[1] = LV((kfo) + (g << 2) + 1, (dcol)); \
        dst[2] = LV((kfo) + (g << 2) + 2, (dcol)); \
        dst[3] = LV((kfo) + (g << 2) + 3, (dcol)); \
        dst[4] = LV((kfo) + 16 + (g << 2) + 0, (dcol)); \
        dst[5] = LV((kfo) + 16 + (g << 2) + 1, (dcol)); \
        dst[6] = LV((kfo) + 16 + (g << 2) + 2, (dcol)); \
        dst[7] = LV((kfo) + 16 + (g << 2) + 3, (dcol)); \
    } while (0)

    #define PEXP(dst, idx, sv, r) do { \
        float e = exp2f(sv[r] - mn); rsum += e; dst[idx] = f2bf(e); \
    } while (0)

    #pragma unroll 1
    for (int t = 0; t < 4; ++t) {
        int pb = t * 64;
        const float* vt = vbase + (size_t)pb * HD;

        // 1) issue all K loads (16 vmem)
        KLD(0) KLD(1) KLD(2) KLD(3)
        // 2) issue V batch A (8 vmem, rows 0..31)
        VLD(0) VLD(1) VLD(2) VLD(3) VLD(4) VLD(5) VLD(6) VLD(7)

        // 3) QK^T MFMAs (drain K progressively; V-A stays in flight)
        f32x4 sc0, sc1, sc2, sc3;
        KMM(sc0, 0); KMM(sc1, 1); KMM(sc2, 2); KMM(sc3, 3);

        // 4) issue V batch B (8 vmem, rows 32..63)
        VLD(8) VLD(9) VLD(10) VLD(11) VLD(12) VLD(13) VLD(14) VLD(15)

        // 5) online softmax (per query = lane&15, partners l^16, l^32)
        float tmax = fmaxf(
            fmaxf(fmaxf(fmaxf(sc0[0], sc0[1]), fmaxf(sc0[2], sc0[3])),
                  fmaxf(fmaxf(sc1[0], sc1[1]), fmaxf(sc1[2], sc1[3]))),
            fmaxf(fmaxf(fmaxf(sc2[0], sc2[1]), fmaxf(sc2[2], sc2[3])),
                  fmaxf(fmaxf(sc3[0], sc3[1]), fmaxf(sc3[2], sc3[3]))));
        tmax = fmaxf(tmax, __shfl_xor(tmax, 16));
        tmax = fmaxf(tmax, __shfl_xor(tmax, 32));
        float mn = fmaxf(m, tmax);
        float alpha = exp2f(m - mn);
        float rsum = 0.f;
        short8 pf0, pf1;
        PEXP(pf0, 0, sc0, 0); PEXP(pf0, 1, sc0, 1); PEXP(pf0, 2, sc0, 2); PEXP(pf0, 3, sc0, 3);
        PEXP(pf0, 4, sc1, 0); PEXP(pf0, 5, sc1, 1); PEXP(pf0, 6, sc1, 2); PEXP(pf0, 7, sc1, 3);
        PEXP(pf1, 0, sc2, 0); PEXP(pf1, 1, sc2, 1); PEXP(pf1, 2, sc2, 2); PEXP(pf1, 3, sc2, 3);
        PEXP(pf1, 4, sc3, 0); PEXP(pf1, 5, sc3, 1); PEXP(pf1, 6, sc3, 2); PEXP(pf1, 7, sc3, 3);
        rsum += __shfl_xor(rsum, 16);
        rsum += __shfl_xor(rsum, 32);
        lsum = lsum * alpha + rsum;
        m = mn;
        o0 *= alpha; o1 *= alpha; o2 *= alpha; o3 *= alpha;

        // 6) stage V batch A to LDS (latency hidden under 3+5)
        VST(0); VST(1); VST(2); VST(3); VST(4); VST(5); VST(6); VST(7);

        // 7) PV for kf=0 (rows 0..31) from LDS
        {
            short8 vfa;
            VFR(vfa, 0, lq);       o0 = MFMA(vfa, pf0, o0);
            VFR(vfa, 0, 16 + lq);  o1 = MFMA(vfa, pf0, o1);
            VFR(vfa, 0, 32 + lq);  o2 = MFMA(vfa, pf0, o2);
            VFR(vfa, 0, 48 + lq);  o3 = MFMA(vfa, pf0, o3);
        }

        // 8) stage V batch B (latency hidden under 5+7)
        VST(8); VST(9); VST(10); VST(11); VST(12); VST(13); VST(14); VST(15);

        // 9) PV for kf=1 (rows 32..63)
        {
            short8 vfb;
            VFR(vfb, 32, lq);       o0 = MFMA(vfb, pf1, o0);
            VFR(vfb, 32, 16 + lq);  o1 = MFMA(vfb, pf1, o1);
            VFR(vfb, 32, 32 + lq);  o2 = MFMA(vfb, pf1, o2);
            VFR(vfb, 32, 48 + lq);  o3 = MFMA(vfb, pf1, o3);
        }
    }

    // ---- the 16 new tokens (wave 0 of split-0 block) ----
    if (split == 0 && wave == 0) {
        const float* kr = knew + (size_t)(b * NS + lq) * HID + h * HD + g * 8;
        float4 ka = *reinterpret_cast<const float4*>(kr);
        float4 kb2 = *reinterpret_cast<const float4*>(kr + 4);
        float4 kc2 = *reinterpret_cast<const float4*>(kr + 32);
        float4 kd2 = *reinterpret_cast<const float4*>(kr + 36);
        short8 af0 = pack8(ka, kb2);
        short8 af1 = pack8(kc2, kd2);
        f32x4 sv = {0.f, 0.f, 0.f, 0.f};
        sv = MFMA(af0, qf0, sv);
        sv = MFMA(af1, qf1, sv);

        float tmax = fmaxf(fmaxf(sv[0], sv[1]), fmaxf(sv[2], sv[3]));
        tmax = fmaxf(tmax, __shfl_xor(tmax, 16));
        tmax = fmaxf(tmax, __shfl_xor(tmax, 32));
        float mn = fmaxf(m, tmax);
        float alpha = exp2f(m - mn);
        float e0 = exp2f(sv[0] - mn);
        float e1 = exp2f(sv[1] - mn);
        float e2 = exp2f(sv[2] - mn);
        float e3 = exp2f(sv[3] - mn);
        float rsum = e0 + e1 + e2 + e3;
        rsum += __shfl_xor(rsum, 16);
        rsum += __shfl_xor(rsum, 32);
        lsum = lsum * alpha + rsum;
        m = mn;
        o0 *= alpha; o1 *= alpha; o2 *= alpha; o3 *= alpha;

        short8 pfT;
        pfT[0] = f2bf(e0); pfT[1] = f2bf(e1); pfT[2] = f2bf(e2); pfT[3] = f2bf(e3);
        pfT[4] = 0; pfT[5] = 0; pfT[6] = 0; pfT[7] = 0;

        const float* vt2 = vnew + (size_t)(b * NS) * HID + h * HD;
        #define LOADVT(dst, dcol) do { \
            dst[0] = f2bf(vt2[(size_t)((g << 2) + 0) * HID + (dcol)]); \
            dst[1] = f2bf(vt2[(size_t)((g << 2) + 1) * HID + (dcol)]); \
            dst[2] = f2bf(vt2[(size_t)((g << 2) + 2) * HID + (dcol)]); \
            dst[3] = f2bf(vt2[(size_t)((g << 2) + 3) * HID + (dcol)]); \
            dst[4] = 0; dst[5] = 0; dst[6] = 0; dst[7] = 0; \
        } while (0)
        short8 vv0, vv1, vv2, vv3;
        LOADVT(vv0, lq); LOADVT(vv1, 16 + lq); LOADVT(vv2, 32 + lq); LOADVT(vv3, 48 + lq);
        #undef LOADVT
        o0 = MFMA(vv0, pfT, o0);
        o1 = MFMA(vv1, pfT, o1);
        o2 = MFMA(vv2, pfT, o2);
        o3 = MFMA(vv3, pfT, o3);
    }

    // ---- merge the 4 wave-partials; s_o unions the V slab (barrier first) ----
    __syncthreads();
    float* so_w = (float*)(lds_raw + wave * VSLAB);   // [16 q][64 d]
    #define STO(ov, dt) do { \
        so_w[lq * 64 + (dt) * 16 + (g << 2) + 0] = ov[0]; \
        so_w[lq * 64 + (dt) * 16 + (g << 2) + 1] = ov[1]; \
        so_w[lq * 64 + (dt) * 16 + (g << 2) + 2] = ov[2]; \
        so_w[lq * 64 + (dt) * 16 + (g << 2) + 3] = ov[3]; \
    } while (0)
    STO(o0, 0); STO(o1, 1); STO(o2, 2); STO(o3, 3);
    #undef STO
    if (g == 0) { s_m[wave][lq] = m; s_l[wave][lq] = lsum; }
    __syncthreads();

    if (wave == 0) {
        float M = fmaxf(fmaxf(s_m[0][lq], s_m[1][lq]), fmaxf(s_m[2][lq], s_m[3][lq]));
        float aw0 = exp2f(s_m[0][lq] - M);
        float aw1 = exp2f(s_m[1][lq] - M);
        float aw2 = exp2f(s_m[2][lq] - M);
        float aw3 = exp2f(s_m[3][lq] - M);
        float L = aw0 * s_l[0][lq] + aw1 * s_l[1][lq] + aw2 * s_l[2][lq] + aw3 * s_l[3][lq];
        const float* so0 = (const float*)(lds_raw + 0 * VSLAB);
        const float* so1 = (const float*)(lds_raw + 1 * VSLAB);
        const float* so2 = (const float*)(lds_raw + 2 * VSLAB);
        const float* so3 = (const float*)(lds_raw + 3 * VSLAB);
        float* pbase = parts + (size_t)bid * PART_STRIDE;
        if (g == 0) { pbase[lq] = M; pbase[16 + lq] = L; }
        for (int dd = 0; dd < 16; ++dd) {
            int di = g * 16 + dd;
            float v = aw0 * so0[lq * 64 + di] + aw1 * so1[lq * 64 + di] +
                      aw2 * so2[lq * 64 + di] + aw3 * so3[lq * 64 + di];
            pbase[32 + lq * 64 + di] = v;
        }
    }
}

// ---------------- merge the 4 split-partials per (b,h) -------------------
__global__ __launch_bounds__(256) void merge_kernel(const float* __restrict__ parts,
                                                    short* __restrict__ attnb) {
    int bh = blockIdx.x;            // b*32 + h
    int tid = threadIdx.x;
    int qi = tid >> 4, ds = (tid & 15) * 4;
    const float* p0 = parts + (size_t)(bh * NSPLIT) * PART_STRIDE;
    const float* p1 = p0 + PART_STRIDE;
    const float* p2 = p1 + PART_STRIDE;
    const float* p3 = p2 + PART_STRIDE;
    float m0 = p0[qi], m1 = p1[qi], m2 = p2[qi], m3 = p3[qi];
    float M = fmaxf(fmaxf(m0, m1), fmaxf(m2, m3));
    float a0 = exp2f(m0 - M), a1 = exp2f(m1 - M), a2 = exp2f(m2 - M), a3 = exp2f(m3 - M);
    float inv = 1.0f / (a0 * p0[16 + qi] + a1 * p1[16 + qi] +
                        a2 * p2[16 + qi] + a3 * p3[16 + qi]);
    int b = bh >> 5, h = bh & 31;
    int base = 32 + qi * 64 + ds;
    float v0 = (a0 * p0[base + 0] + a1 * p1[base + 0] + a2 * p2[base + 0] + a3 * p3[base + 0]) * inv;
    float v1 = (a0 * p0[base + 1] + a1 * p1[base + 1] + a2 * p2[base + 1] + a3 * p3[base + 1]) * inv;
    float v2 = (a0 * p0[base + 2] + a1 * p1[base + 2] + a2 * p2[base + 2] + a3 * p3[base + 2]) * inv;
    float v3 = (a0 * p0[base + 3] + a1 * p1[base + 3] + a2 * p2[base + 3] + a3 * p3[base + 3]) * inv;
    short4v o;
    o[0] = f2bf(v0); o[1] = f2bf(v1); o[2] = f2bf(v2); o[3] = f2bf(v3);
    *reinterpret_cast<short4v*>(attnb + (size_t)(b * NS + qi) * HID + h * HD + ds) = o;
}

extern "C" void kernel_launch(void* const* d_in, const int* in_sizes, int n_in,
                              void* d_out, int out_size, void* d_ws, size_t ws_size,
                              hipStream_t stream) {
    const float* hs     = (const float*)d_in[0];
    const float* past_k = (const float*)d_in[1];
    const float* past_v = (const float*)d_in[2];
    const float* wq     = (const float*)d_in[3];
    const float* wk     = (const float*)d_in[4];
    const float* wv     = (const float*)d_in[5];
    const float* wo     = (const float*)d_in[6];
    float* out = (float*)d_out;

    float* qb = (float*)d_ws;                 // 128x2048 f32
    float* kn = qb + 128 * 2048;              // 128x2048 f32
    float* vn = kn + 128 * 2048;              // 128x2048 f32
    short* hsb   = (short*)(vn + 128 * 2048); // 128x2048 bf16
    short* attnb = hsb + 128 * 2048;          // 128x2048 bf16
    float* parts = (float*)(attnb + 128 * 2048); // 1024 * PART_STRIDE f32

    // zero atomic-accumulated outputs (graph-capture-safe async memsets)
    hipMemsetAsync(qb, 0, (size_t)3 * 128 * 2048 * sizeof(float), stream);
    hipMemsetAsync(out, 0, (size_t)128 * 2048 * sizeof(float), stream);

    cvt_kernel<<<256, 256, 0, stream>>>(hs, hsb);
    proj_kernel<<<1536, 128, 0, stream>>>(hsb, wq, wk, wv, qb, kn, vn);
    attn_kernel<<<256 * NSPLIT, 256, 0, stream>>>(qb, kn, vn, past_k, past_v, parts);
    merge_kernel<<<256, 256, 0, stream>>>(parts, attnb);
    proj_kernel<<<512, 128, 0, stream>>>(attnb, wo, wo, wo, out, out, out);
}

// Round 8
// 170.276 us; speedup vs baseline: 1.2343x; 1.2343x over previous
//
#include <hip/hip_runtime.h>
#include <hip/hip_bf16.h>
#include <stdint.h>

#define HID 2048
#define NH  32
#define HD  64
#define NB  8
#define NS  16
#define PAST 4096

// log2(e) / sqrt(D) = 1.4426950408889634 / 8
#define QSCALE 0.18033688011112042591f

typedef __attribute__((ext_vector_type(8))) short short8;
typedef __attribute__((ext_vector_type(4))) short short4v;
typedef __attribute__((ext_vector_type(4))) float f32x4;

#define MFMA(a, b, c) __builtin_amdgcn_mfma_f32_16x16x32_bf16((a), (b), (c), 0, 0, 0)

#define PART_STRIDE 1088  // 16 m + 16 l + 16*64 O + pad, floats
#define NSPLIT 4          // attn splits per (b,h); 1024 pos per split
#define NTILES 16         // 64-pos tiles per split

static __device__ __forceinline__ short f2bf(float f) {
    __hip_bfloat16 h = __float2bfloat16(f);
    return *reinterpret_cast<short*>(&h);
}

// async HBM -> LDS, 16B per lane; dest = uniform base + lane*16 (m104)
static __device__ __forceinline__ void gload_lds16(const float* g, float* l) {
    __builtin_amdgcn_global_load_lds(
        (const __attribute__((address_space(1))) void*)(g),
        (__attribute__((address_space(3))) void*)(l),
        16, 0, 0);
}

static __device__ __forceinline__ short8 pack8(float4 a, float4 b) {
    short8 r;
    r[0] = f2bf(a.x); r[1] = f2bf(a.y); r[2] = f2bf(a.z); r[3] = f2bf(a.w);
    r[4] = f2bf(b.x); r[5] = f2bf(b.y); r[6] = f2bf(b.z); r[7] = f2bf(b.w);
    return r;
}

static __device__ __forceinline__ short8 pack8s(float4 a, float4 b, float s) {
    short8 r;
    r[0] = f2bf(a.x * s); r[1] = f2bf(a.y * s); r[2] = f2bf(a.z * s); r[3] = f2bf(a.w * s);
    r[4] = f2bf(b.x * s); r[5] = f2bf(b.y * s); r[6] = f2bf(b.z * s); r[7] = f2bf(b.w * s);
    return r;
}

// ---------------- hidden fp32 -> bf16 ----------------
__global__ __launch_bounds__(256) void cvt_kernel(const float* __restrict__ in,
                                                  short* __restrict__ out) {
    int i = (blockIdx.x * 256 + threadIdx.x) * 4;
    float4 v = *reinterpret_cast<const float4*>(in + i);
    short4v o;
    o[0] = f2bf(v.x); o[1] = f2bf(v.y); o[2] = f2bf(v.z); o[3] = f2bf(v.w);
    *reinterpret_cast<short4v*>(out + i) = o;
}

// ------- Y += Xbf16 @ W^T  (M=128, K-split x4, N=16 per block), atomic -----
__global__ __launch_bounds__(128) void proj_kernel(
        const short* __restrict__ X,
        const float* __restrict__ W0, const float* __restrict__ W1,
        const float* __restrict__ W2,
        float* __restrict__ Y0, float* __restrict__ Y1, float* __restrict__ Y2) {
    int mat   = blockIdx.x >> 9;
    int rest  = blockIdx.x & 511;
    int strip = rest >> 2, ks = rest & 3;
    int nbase = strip * 16;
    int k0    = ks * 512;
    const float* W = (mat == 0) ? W0 : (mat == 1) ? W1 : W2;
    float*       Y = (mat == 0) ? Y0 : (mat == 1) ? Y1 : Y2;

    int lane = threadIdx.x & 63;
    int wave = threadIdx.x >> 6;
    int lr = lane & 15, g = lane >> 4;

    f32x4 acc0 = {0.f, 0.f, 0.f, 0.f};
    f32x4 acc1 = {0.f, 0.f, 0.f, 0.f};
    f32x4 acc2 = {0.f, 0.f, 0.f, 0.f};
    f32x4 acc3 = {0.f, 0.f, 0.f, 0.f};

    const short* xr = X + (size_t)(wave * 64 + lr) * HID + g * 8 + k0;
    const float* wr = W + (size_t)(nbase + lr) * HID + g * 8 + k0;

    #pragma unroll 4
    for (int kc = 0; kc < 512; kc += 32) {
        float4 w0 = *reinterpret_cast<const float4*>(wr + kc);
        float4 w1 = *reinterpret_cast<const float4*>(wr + kc + 4);
        short8 bb = pack8(w0, w1);
        short8 a0 = *reinterpret_cast<const short8*>(xr + kc);
        short8 a1 = *reinterpret_cast<const short8*>(xr + (size_t)16 * HID + kc);
        short8 a2 = *reinterpret_cast<const short8*>(xr + (size_t)32 * HID + kc);
        short8 a3 = *reinterpret_cast<const short8*>(xr + (size_t)48 * HID + kc);
        acc0 = MFMA(a0, bb, acc0);
        acc1 = MFMA(a1, bb, acc1);
        acc2 = MFMA(a2, bb, acc2);
        acc3 = MFMA(a3, bb, acc3);
    }
    #define STACC(accv, f) do { \
        atomicAdd(&Y[(size_t)(wave * 64 + (f) * 16 + (g << 2) + 0) * HID + nbase + lr], accv[0]); \
        atomicAdd(&Y[(size_t)(wave * 64 + (f) * 16 + (g << 2) + 1) * HID + nbase + lr], accv[1]); \
        atomicAdd(&Y[(size_t)(wave * 64 + (f) * 16 + (g << 2) + 2) * HID + nbase + lr], accv[2]); \
        atomicAdd(&Y[(size_t)(wave * 64 + (f) * 16 + (g << 2) + 3) * HID + nbase + lr], accv[3]); \
    } while (0)
    STACC(acc0, 0); STACC(acc1, 1); STACC(acc2, 2); STACC(acc3, 3);
    #undef STACC
}

// ---------------- fused attention, 4 blocks per (b,h) -------------------
// blockIdx.x = bh*4 + split. 256 threads = 4 waves, cooperative 64-pos tiles:
// each tile's V (64x64 f32, 16KB) is DMA'd to LDS via global_load_lds
// (double-buffered); wave w owns positions [w*16, w*16+16) of every tile.
__global__ __launch_bounds__(256, 4) void attn_kernel(
        const float* __restrict__ q,
        const float* __restrict__ knew, const float* __restrict__ vnew,
        const float* __restrict__ pastK, const float* __restrict__ pastV,
        float* __restrict__ parts) {
    __shared__ __align__(16) float lds_v[2][64 * 64];   // V fp32 dbuf (32KB)
    __shared__ float s_m[4][16];
    __shared__ float s_l[4][16];

    int bid = blockIdx.x;
    int bh = bid >> 2, split = bid & 3;
    int b = bh >> 5, h = bh & 31;
    int wave = threadIdx.x >> 6, lane = threadIdx.x & 63;
    int lq = lane & 15, g = lane >> 4;

    // Q fragments (B operand of swapped QK^T), pre-scaled by log2(e)/8
    const float* qp = q + (size_t)(b * NS + lq) * HID + h * HD + g * 8;
    short8 qf0, qf1;
    {
        float4 a0 = *reinterpret_cast<const float4*>(qp);
        float4 a1 = *reinterpret_cast<const float4*>(qp + 4);
        float4 a2 = *reinterpret_cast<const float4*>(qp + 32);
        float4 a3 = *reinterpret_cast<const float4*>(qp + 36);
        qf0 = pack8s(a0, a1, QSCALE);
        qf1 = pack8s(a2, a3, QSCALE);
    }

    f32x4 o0 = {0.f, 0.f, 0.f, 0.f};
    f32x4 o1 = {0.f, 0.f, 0.f, 0.f};
    f32x4 o2 = {0.f, 0.f, 0.f, 0.f};
    f32x4 o3 = {0.f, 0.f, 0.f, 0.f};
    float m = -__builtin_inff(), lsum = 0.0f;

    const float* ksplit = pastK + (size_t)bh * PAST * HD + (size_t)split * 1024 * HD;
    const float* vsplit = pastV + (size_t)bh * PAST * HD + (size_t)split * 1024 * HD;

    // stage tile tt's V into dstf: 16 chunks of 1KB; wave issues chunks w*4..w*4+3
    #define STAGE(tt, dstf) do { \
        const float* gsrc_ = vsplit + (size_t)(tt) * 64 * HD; \
        gload_lds16(gsrc_ + (wave * 4 + 0) * 256 + lane * 4, (dstf) + (wave * 4 + 0) * 256); \
        gload_lds16(gsrc_ + (wave * 4 + 1) * 256 + lane * 4, (dstf) + (wave * 4 + 1) * 256); \
        gload_lds16(gsrc_ + (wave * 4 + 2) * 256 + lane * 4, (dstf) + (wave * 4 + 2) * 256); \
        gload_lds16(gsrc_ + (wave * 4 + 3) * 256 + lane * 4, (dstf) + (wave * 4 + 3) * 256); \
    } while (0)

    STAGE(0, lds_v[0]);
    __syncthreads();

    int cur = 0;
    #pragma unroll 1
    for (int t = 0; t < NTILES; ++t) {
        if (t + 1 < NTILES) STAGE(t + 1, lds_v[cur ^ 1]);

        // ---- K rows for this wave's 16 positions; QK^T (swapped) ----
        const float* kr = ksplit + (size_t)(t * 64 + wave * 16 + lq) * HD + (g << 3);
        float4 ka = *reinterpret_cast<const float4*>(kr);
        float4 kb = *reinterpret_cast<const float4*>(kr + 4);
        float4 kc = *reinterpret_cast<const float4*>(kr + 32);
        float4 kd = *reinterpret_cast<const float4*>(kr + 36);
        short8 af0 = pack8(ka, kb);
        short8 af1 = pack8(kc, kd);
        f32x4 sv = {0.f, 0.f, 0.f, 0.f};
        sv = MFMA(af0, qf0, sv);
        sv = MFMA(af1, qf1, sv);

        // ---- online softmax (positions p = g*4+r of this wave's 16; q = lq) ----
        float tmax = fmaxf(fmaxf(sv[0], sv[1]), fmaxf(sv[2], sv[3]));
        tmax = fmaxf(tmax, __shfl_xor(tmax, 16));
        tmax = fmaxf(tmax, __shfl_xor(tmax, 32));
        float mn = fmaxf(m, tmax);
        float alpha = exp2f(m - mn);
        float e0 = exp2f(sv[0] - mn);
        float e1 = exp2f(sv[1] - mn);
        float e2 = exp2f(sv[2] - mn);
        float e3 = exp2f(sv[3] - mn);
        float rsum = e0 + e1 + e2 + e3;
        rsum += __shfl_xor(rsum, 16);
        rsum += __shfl_xor(rsum, 32);
        lsum = lsum * alpha + rsum;
        m = mn;
        o0 *= alpha; o1 *= alpha; o2 *= alpha; o3 *= alpha;

        short8 pf;
        pf[0] = f2bf(e0); pf[1] = f2bf(e1); pf[2] = f2bf(e2); pf[3] = f2bf(e3);
        pf[4] = 0; pf[5] = 0; pf[6] = 0; pf[7] = 0;

        // ---- PV from LDS (rows wave*16 + g*4 + j), zero-padded k-slots 4..7 ----
        const float* vc = lds_v[cur] + (wave * 16 + (g << 2)) * 64;
        #define VFR(dst, dcol) do { \
            dst[0] = f2bf(vc[0 * 64 + (dcol)]); \
            dst[1] = f2bf(vc[1 * 64 + (dcol)]); \
            dst[2] = f2bf(vc[2 * 64 + (dcol)]); \
            dst[3] = f2bf(vc[3 * 64 + (dcol)]); \
            dst[4] = 0; dst[5] = 0; dst[6] = 0; dst[7] = 0; \
        } while (0)
        {
            short8 vf;
            VFR(vf, lq);       o0 = MFMA(vf, pf, o0);
            VFR(vf, 16 + lq);  o1 = MFMA(vf, pf, o1);
            VFR(vf, 32 + lq);  o2 = MFMA(vf, pf, o2);
            VFR(vf, 48 + lq);  o3 = MFMA(vf, pf, o3);
        }
        #undef VFR

        __syncthreads();   // drains stage of t+1; LDS buffer handoff
        cur ^= 1;
    }
    #undef STAGE

    // ---- the 16 new tokens (wave 0 of split-0 block) ----
    if (split == 0 && wave == 0) {
        const float* kr = knew + (size_t)(b * NS + lq) * HID + h * HD + g * 8;
        float4 ka = *reinterpret_cast<const float4*>(kr);
        float4 kb2 = *reinterpret_cast<const float4*>(kr + 4);
        float4 kc2 = *reinterpret_cast<const float4*>(kr + 32);
        float4 kd2 = *reinterpret_cast<const float4*>(kr + 36);
        short8 af0 = pack8(ka, kb2);
        short8 af1 = pack8(kc2, kd2);
        f32x4 sv = {0.f, 0.f, 0.f, 0.f};
        sv = MFMA(af0, qf0, sv);
        sv = MFMA(af1, qf1, sv);

        float tmax = fmaxf(fmaxf(sv[0], sv[1]), fmaxf(sv[2], sv[3]));
        tmax = fmaxf(tmax, __shfl_xor(tmax, 16));
        tmax = fmaxf(tmax, __shfl_xor(tmax, 32));
        float mn = fmaxf(m, tmax);
        float alpha = exp2f(m - mn);
        float e0 = exp2f(sv[0] - mn);
        float e1 = exp2f(sv[1] - mn);
        float e2 = exp2f(sv[2] - mn);
        float e3 = exp2f(sv[3] - mn);
        float rsum = e0 + e1 + e2 + e3;
        rsum += __shfl_xor(rsum, 16);
        rsum += __shfl_xor(rsum, 32);
        lsum = lsum * alpha + rsum;
        m = mn;
        o0 *= alpha; o1 *= alpha; o2 *= alpha; o3 *= alpha;

        short8 pfT;
        pfT[0] = f2bf(e0); pfT[1] = f2bf(e1); pfT[2] = f2bf(e2); pfT[3] = f2bf(e3);
        pfT[4] = 0; pfT[5] = 0; pfT[6] = 0; pfT[7] = 0;

        const float* vt2 = vnew + (size_t)(b * NS) * HID + h * HD;
        #define LOADVT(dst, dcol) do { \
            dst[0] = f2bf(vt2[(size_t)((g << 2) + 0) * HID + (dcol)]); \
            dst[1] = f2bf(vt2[(size_t)((g << 2) + 1) * HID + (dcol)]); \
            dst[2] = f2bf(vt2[(size_t)((g << 2) + 2) * HID + (dcol)]); \
            dst[3] = f2bf(vt2[(size_t)((g << 2) + 3) * HID + (dcol)]); \
            dst[4] = 0; dst[5] = 0; dst[6] = 0; dst[7] = 0; \
        } while (0)
        short8 vv0, vv1, vv2, vv3;
        LOADVT(vv0, lq); LOADVT(vv1, 16 + lq); LOADVT(vv2, 32 + lq); LOADVT(vv3, 48 + lq);
        #undef LOADVT
        o0 = MFMA(vv0, pfT, o0);
        o1 = MFMA(vv1, pfT, o1);
        o2 = MFMA(vv2, pfT, o2);
        o3 = MFMA(vv3, pfT, o3);
    }

    // ---- merge the 4 wave-partials; s_o unions the (drained) V buffers ----
    float* so_w = (float*)lds_v[0] + wave * 1024;   // [16 q][64 d] per wave
    #define STO(ov, dt) do { \
        so_w[lq * 64 + (dt) * 16 + (g << 2) + 0] = ov[0]; \
        so_w[lq * 64 + (dt) * 16 + (g << 2) + 1] = ov[1]; \
        so_w[lq * 64 + (dt) * 16 + (g << 2) + 2] = ov[2]; \
        so_w[lq * 64 + (dt) * 16 + (g << 2) + 3] = ov[3]; \
    } while (0)
    STO(o0, 0); STO(o1, 1); STO(o2, 2); STO(o3, 3);
    #undef STO
    if (g == 0) { s_m[wave][lq] = m; s_l[wave][lq] = lsum; }
    __syncthreads();

    if (wave == 0) {
        float M = fmaxf(fmaxf(s_m[0][lq], s_m[1][lq]), fmaxf(s_m[2][lq], s_m[3][lq]));
        float aw0 = exp2f(s_m[0][lq] - M);
        float aw1 = exp2f(s_m[1][lq] - M);
        float aw2 = exp2f(s_m[2][lq] - M);
        float aw3 = exp2f(s_m[3][lq] - M);
        float L = aw0 * s_l[0][lq] + aw1 * s_l[1][lq] + aw2 * s_l[2][lq] + aw3 * s_l[3][lq];
        const float* so0 = (const float*)lds_v[0] + 0 * 1024;
        const float* so1 = (const float*)lds_v[0] + 1 * 1024;
        const float* so2 = (const float*)lds_v[0] + 2 * 1024;
        const float* so3 = (const float*)lds_v[0] + 3 * 1024;
        float* pbase = parts + (size_t)bid * PART_STRIDE;
        if (g == 0) { pbase[lq] = M; pbase[16 + lq] = L; }
        for (int dd = 0; dd < 16; ++dd) {
            int di = g * 16 + dd;
            float v = aw0 * so0[lq * 64 + di] + aw1 * so1[lq * 64 + di] +
                      aw2 * so2[lq * 64 + di] + aw3 * so3[lq * 64 + di];
            pbase[32 + lq * 64 + di] = v;
        }
    }
}

// ---------------- merge the 4 split-partials per (b,h) -------------------
__global__ __launch_bounds__(256) void merge_kernel(const float* __restrict__ parts,
                                                    short* __restrict__ attnb) {
    int bh = blockIdx.x;            // b*32 + h
    int tid = threadIdx.x;
    int qi = tid >> 4, ds = (tid & 15) * 4;
    const float* p0 = parts + (size_t)(bh * NSPLIT) * PART_STRIDE;
    const float* p1 = p0 + PART_STRIDE;
    const float* p2 = p1 + PART_STRIDE;
    const float* p3 = p2 + PART_STRIDE;
    float m0 = p0[qi], m1 = p1[qi], m2 = p2[qi], m3 = p3[qi];
    float M = fmaxf(fmaxf(m0, m1), fmaxf(m2, m3));
    float a0 = exp2f(m0 - M), a1 = exp2f(m1 - M), a2 = exp2f(m2 - M), a3 = exp2f(m3 - M);
    float inv = 1.0f / (a0 * p0[16 + qi] + a1 * p1[16 + qi] +
                        a2 * p2[16 + qi] + a3 * p3[16 + qi]);
    int b = bh >> 5, h = bh & 31;
    int base = 32 + qi * 64 + ds;
    float v0 = (a0 * p0[base + 0] + a1 * p1[base + 0] + a2 * p2[base + 0] + a3 * p3[base + 0]) * inv;
    float v1 = (a0 * p0[base + 1] + a1 * p1[base + 1] + a2 * p2[base + 1] + a3 * p3[base + 1]) * inv;
    float v2 = (a0 * p0[base + 2] + a1 * p1[base + 2] + a2 * p2[base + 2] + a3 * p3[base + 2]) * inv;
    float v3 = (a0 * p0[base + 3] + a1 * p1[base + 3] + a2 * p2[base + 3] + a3 * p3[base + 3]) * inv;
    short4v o;
    o[0] = f2bf(v0); o[1] = f2bf(v1); o[2] = f2bf(v2); o[3] = f2bf(v3);
    *reinterpret_cast<short4v*>(attnb + (size_t)(b * NS + qi) * HID + h * HD + ds) = o;
}

extern "C" void kernel_launch(void* const* d_in, const int* in_sizes, int n_in,
                              void* d_out, int out_size, void* d_ws, size_t ws_size,
                              hipStream_t stream) {
    const float* hs     = (const float*)d_in[0];
    const float* past_k = (const float*)d_in[1];
    const float* past_v = (const float*)d_in[2];
    const float* wq     = (const float*)d_in[3];
    const float* wk     = (const float*)d_in[4];
    const float* wv     = (const float*)d_in[5];
    const float* wo     = (const float*)d_in[6];
    float* out = (float*)d_out;

    float* qb = (float*)d_ws;                 // 128x2048 f32
    float* kn = qb + 128 * 2048;              // 128x2048 f32
    float* vn = kn + 128 * 2048;              // 128x2048 f32
    short* hsb   = (short*)(vn + 128 * 2048); // 128x2048 bf16
    short* attnb = hsb + 128 * 2048;          // 128x2048 bf16
    float* parts = (float*)(attnb + 128 * 2048); // 1024 * PART_STRIDE f32

    // zero atomic-accumulated outputs (graph-capture-safe async memsets)
    hipMemsetAsync(qb, 0, (size_t)3 * 128 * 2048 * sizeof(float), stream);
    hipMemsetAsync(out, 0, (size_t)128 * 2048 * sizeof(float), stream);

    cvt_kernel<<<256, 256, 0, stream>>>(hs, hsb);
    proj_kernel<<<1536, 128, 0, stream>>>(hsb, wq, wk, wv, qb, kn, vn);
    attn_kernel<<<256 * NSPLIT, 256, 0, stream>>>(qb, kn, vn, past_k, past_v, parts);
    merge_kernel<<<256, 256, 0, stream>>>(parts, attnb);
    proj_kernel<<<512, 128, 0, stream>>>(attnb, wo, wo, wo, out, out, out);
}

// Round 9
// 169.045 us; speedup vs baseline: 1.2433x; 1.0073x over previous
//
#include <hip/hip_runtime.h>
#include <hip/hip_bf16.h>
#include <stdint.h>

#define HID 2048
#define NH  32
#define HD  64
#define NB  8
#define NS  16
#define PAST 4096

// log2(e) / sqrt(D) = 1.4426950408889634 / 8
#define QSCALE 0.18033688011112042591f

typedef __attribute__((ext_vector_type(8))) short short8;
typedef __attribute__((ext_vector_type(4))) short short4v;
typedef __attribute__((ext_vector_type(4))) float f32x4;

#define MFMA(a, b, c) __builtin_amdgcn_mfma_f32_16x16x32_bf16((a), (b), (c), 0, 0, 0)

#define PART_STRIDE 1088  // 16 m + 16 l + 16*64 O + pad, floats
#define NSPLIT 4          // attn splits per (b,h); 1024 pos per split
#define MATSZ (128 * HID) // elements of one projection output

static __device__ __forceinline__ short f2bf(float f) {
    __hip_bfloat16 h = __float2bfloat16(f);
    return *reinterpret_cast<short*>(&h);
}

// async HBM -> LDS, 16B per lane; dest = uniform base + lane*16 (m104)
static __device__ __forceinline__ void gload_lds16(const float* g, float* l) {
    __builtin_amdgcn_global_load_lds(
        (const __attribute__((address_space(1))) void*)(g),
        (__attribute__((address_space(3))) void*)(l),
        16, 0, 0);
}

static __device__ __forceinline__ short8 pack8(float4 a, float4 b) {
    short8 r;
    r[0] = f2bf(a.x); r[1] = f2bf(a.y); r[2] = f2bf(a.z); r[3] = f2bf(a.w);
    r[4] = f2bf(b.x); r[5] = f2bf(b.y); r[6] = f2bf(b.z); r[7] = f2bf(b.w);
    return r;
}

static __device__ __forceinline__ short8 pack8s(float4 a, float4 b, float s) {
    short8 r;
    r[0] = f2bf(a.x * s); r[1] = f2bf(a.y * s); r[2] = f2bf(a.z * s); r[3] = f2bf(a.w * s);
    r[4] = f2bf(b.x * s); r[5] = f2bf(b.y * s); r[6] = f2bf(b.z * s); r[7] = f2bf(b.w * s);
    return r;
}

// ---------------- hidden fp32 -> bf16 ----------------
__global__ __launch_bounds__(256) void cvt_kernel(const float* __restrict__ in,
                                                  short* __restrict__ out) {
    int i = (blockIdx.x * 256 + threadIdx.x) * 4;
    float4 v = *reinterpret_cast<const float4*>(in + i);
    short4v o;
    o[0] = f2bf(v.x); o[1] = f2bf(v.y); o[2] = f2bf(v.z); o[3] = f2bf(v.w);
    *reinterpret_cast<short4v*>(out + i) = o;
}

// ------- Ypart[mat*4+ks] = Xbf16 @ W^T slice (M=128, K-split x4, N=16) -----
// blockIdx.x = mat*512 + strip*4 + ks.  128 threads (2 waves, M=64 each).
// Writes PARTIALS (no atomics); merge4_kernel sums the 4 K-slices.
__global__ __launch_bounds__(128) void proj_kernel(
        const short* __restrict__ X,
        const float* __restrict__ W0, const float* __restrict__ W1,
        const float* __restrict__ W2,
        float* __restrict__ Yp) {
    int mat   = blockIdx.x >> 9;
    int rest  = blockIdx.x & 511;
    int strip = rest >> 2, ks = rest & 3;
    int nbase = strip * 16;
    int k0    = ks * 512;
    const float* W = (mat == 0) ? W0 : (mat == 1) ? W1 : W2;
    float* Y = Yp + (size_t)(mat * 4 + ks) * MATSZ;

    int lane = threadIdx.x & 63;
    int wave = threadIdx.x >> 6;
    int lr = lane & 15, g = lane >> 4;

    f32x4 acc0 = {0.f, 0.f, 0.f, 0.f};
    f32x4 acc1 = {0.f, 0.f, 0.f, 0.f};
    f32x4 acc2 = {0.f, 0.f, 0.f, 0.f};
    f32x4 acc3 = {0.f, 0.f, 0.f, 0.f};

    const short* xr = X + (size_t)(wave * 64 + lr) * HID + g * 8 + k0;
    const float* wr = W + (size_t)(nbase + lr) * HID + g * 8 + k0;

    #pragma unroll 4
    for (int kc = 0; kc < 512; kc += 32) {
        float4 w0 = *reinterpret_cast<const float4*>(wr + kc);
        float4 w1 = *reinterpret_cast<const float4*>(wr + kc + 4);
        short8 bb = pack8(w0, w1);
        short8 a0 = *reinterpret_cast<const short8*>(xr + kc);
        short8 a1 = *reinterpret_cast<const short8*>(xr + (size_t)16 * HID + kc);
        short8 a2 = *reinterpret_cast<const short8*>(xr + (size_t)32 * HID + kc);
        short8 a3 = *reinterpret_cast<const short8*>(xr + (size_t)48 * HID + kc);
        acc0 = MFMA(a0, bb, acc0);
        acc1 = MFMA(a1, bb, acc1);
        acc2 = MFMA(a2, bb, acc2);
        acc3 = MFMA(a3, bb, acc3);
    }
    #define STACC(accv, f) do { \
        Y[(size_t)(wave * 64 + (f) * 16 + (g << 2) + 0) * HID + nbase + lr] = accv[0]; \
        Y[(size_t)(wave * 64 + (f) * 16 + (g << 2) + 1) * HID + nbase + lr] = accv[1]; \
        Y[(size_t)(wave * 64 + (f) * 16 + (g << 2) + 2) * HID + nbase + lr] = accv[2]; \
        Y[(size_t)(wave * 64 + (f) * 16 + (g << 2) + 3) * HID + nbase + lr] = accv[3]; \
    } while (0)
    STACC(acc0, 0); STACC(acc1, 1); STACC(acc2, 2); STACC(acc3, 3);
    #undef STACC
}

// -------- sum the 4 K-slice partials: Y = sum_ks Yp[mat*4+ks] -------------
// grid = nmats*256 blocks of 256 threads; 4 f32 per thread.
__global__ __launch_bounds__(256) void merge4_kernel(
        const float* __restrict__ Yp,
        float* __restrict__ Y0, float* __restrict__ Y1, float* __restrict__ Y2) {
    int mat = blockIdx.x >> 8;
    int blk = blockIdx.x & 255;
    float* Y = (mat == 0) ? Y0 : (mat == 1) ? Y1 : Y2;
    const float* P = Yp + (size_t)mat * 4 * MATSZ;
    int idx = blk * 1024 + threadIdx.x * 4;
    float4 a = *reinterpret_cast<const float4*>(P + idx);
    float4 b = *reinterpret_cast<const float4*>(P + MATSZ + idx);
    float4 c = *reinterpret_cast<const float4*>(P + 2 * MATSZ + idx);
    float4 d = *reinterpret_cast<const float4*>(P + 3 * MATSZ + idx);
    float4 s;
    s.x = a.x + b.x + c.x + d.x;
    s.y = a.y + b.y + c.y + d.y;
    s.z = a.z + b.z + c.z + d.z;
    s.w = a.w + b.w + c.w + d.w;
    *reinterpret_cast<float4*>(Y + idx) = s;
}

// ---------------- fused attention, 4 blocks per (b,h) -------------------
// blockIdx.x = bh*4 + split. 256 threads = 4 waves. Per 64-pos tile, wave w
// owns positions [w*16, w*16+16): it stages exactly those V rows via
// global_load_lds (wave-private -> NO in-loop barriers; counted vmcnt
// pipelining), K is register-double-buffered one tile ahead.
__global__ __launch_bounds__(256, 4) void attn_kernel(
        const float* __restrict__ q,
        const float* __restrict__ knew, const float* __restrict__ vnew,
        const float* __restrict__ pastK, const float* __restrict__ pastV,
        float* __restrict__ parts) {
    __shared__ __align__(16) float lds_v[2][64 * 64];   // V fp32 dbuf (32KB)
    __shared__ float s_m[4][16];
    __shared__ float s_l[4][16];

    int bid = blockIdx.x;
    int bh = bid >> 2, split = bid & 3;
    int b = bh >> 5, h = bh & 31;
    int wave = threadIdx.x >> 6, lane = threadIdx.x & 63;
    int lq = lane & 15, g = lane >> 4;

    // Q fragments (B operand of swapped QK^T), pre-scaled by log2(e)/8
    const float* qp = q + (size_t)(b * NS + lq) * HID + h * HD + g * 8;
    short8 qf0, qf1;
    {
        float4 a0 = *reinterpret_cast<const float4*>(qp);
        float4 a1 = *reinterpret_cast<const float4*>(qp + 4);
        float4 a2 = *reinterpret_cast<const float4*>(qp + 32);
        float4 a3 = *reinterpret_cast<const float4*>(qp + 36);
        qf0 = pack8s(a0, a1, QSCALE);
        qf1 = pack8s(a2, a3, QSCALE);
    }

    f32x4 o0 = {0.f, 0.f, 0.f, 0.f};
    f32x4 o1 = {0.f, 0.f, 0.f, 0.f};
    f32x4 o2 = {0.f, 0.f, 0.f, 0.f};
    f32x4 o3 = {0.f, 0.f, 0.f, 0.f};
    float m = -__builtin_inff(), lsum = 0.0f;

    const float* ksplit = pastK + (size_t)bh * PAST * HD + (size_t)split * 1024 * HD;
    const float* vsplit = pastV + (size_t)bh * PAST * HD + (size_t)split * 1024 * HD;

    // K rows for tile T -> 4 named float4 (issued one tile ahead)
    #define ISSUE_K(T, A, Bv, C, D) do { \
        const float* kr_ = ksplit + (size_t)((T) * 64 + wave * 16 + lq) * HD + (g << 3); \
        A  = *reinterpret_cast<const float4*>(kr_); \
        Bv = *reinterpret_cast<const float4*>(kr_ + 4); \
        C  = *reinterpret_cast<const float4*>(kr_ + 32); \
        D  = *reinterpret_cast<const float4*>(kr_ + 36); \
    } while (0)

    // stage tile T's V rows [wave*16, wave*16+16) into dstf (wave-private)
    #define STAGE(T, dstf) do { \
        const float* gsrc_ = vsplit + (size_t)(T) * 64 * HD; \
        gload_lds16(gsrc_ + (wave * 4 + 0) * 256 + lane * 4, (dstf) + (wave * 4 + 0) * 256); \
        gload_lds16(gsrc_ + (wave * 4 + 1) * 256 + lane * 4, (dstf) + (wave * 4 + 1) * 256); \
        gload_lds16(gsrc_ + (wave * 4 + 2) * 256 + lane * 4, (dstf) + (wave * 4 + 2) * 256); \
        gload_lds16(gsrc_ + (wave * 4 + 3) * 256 + lane * 4, (dstf) + (wave * 4 + 3) * 256); \
    } while (0)

    // full tile compute using K regs (A..D) and V in lds_v[BUF]
    #define COMPUTE(A, Bv, C, D, BUF) do { \
        short8 af0 = pack8(A, Bv); \
        short8 af1 = pack8(C, D); \
        f32x4 sv = {0.f, 0.f, 0.f, 0.f}; \
        sv = MFMA(af0, qf0, sv); \
        sv = MFMA(af1, qf1, sv); \
        float tmax = fmaxf(fmaxf(sv[0], sv[1]), fmaxf(sv[2], sv[3])); \
        tmax = fmaxf(tmax, __shfl_xor(tmax, 16)); \
        tmax = fmaxf(tmax, __shfl_xor(tmax, 32)); \
        float mn = fmaxf(m, tmax); \
        float alpha = exp2f(m - mn); \
        float e0 = exp2f(sv[0] - mn); \
        float e1 = exp2f(sv[1] - mn); \
        float e2 = exp2f(sv[2] - mn); \
        float e3 = exp2f(sv[3] - mn); \
        float rsum = e0 + e1 + e2 + e3; \
        rsum += __shfl_xor(rsum, 16); \
        rsum += __shfl_xor(rsum, 32); \
        lsum = lsum * alpha + rsum; \
        m = mn; \
        o0 *= alpha; o1 *= alpha; o2 *= alpha; o3 *= alpha; \
        short8 pf; \
        pf[0] = f2bf(e0); pf[1] = f2bf(e1); pf[2] = f2bf(e2); pf[3] = f2bf(e3); \
        pf[4] = 0; pf[5] = 0; pf[6] = 0; pf[7] = 0; \
        const float* vc = lds_v[BUF] + (wave * 16 + (g << 2)) * 64; \
        short8 vf; \
        vf[0] = f2bf(vc[0 * 64 + lq]);      vf[1] = f2bf(vc[1 * 64 + lq]); \
        vf[2] = f2bf(vc[2 * 64 + lq]);      vf[3] = f2bf(vc[3 * 64 + lq]); \
        vf[4] = 0; vf[5] = 0; vf[6] = 0; vf[7] = 0; \
        o0 = MFMA(vf, pf, o0); \
        vf[0] = f2bf(vc[0 * 64 + 16 + lq]); vf[1] = f2bf(vc[1 * 64 + 16 + lq]); \
        vf[2] = f2bf(vc[2 * 64 + 16 + lq]); vf[3] = f2bf(vc[3 * 64 + 16 + lq]); \
        o1 = MFMA(vf, pf, o1); \
        vf[0] = f2bf(vc[0 * 64 + 32 + lq]); vf[1] = f2bf(vc[1 * 64 + 32 + lq]); \
        vf[2] = f2bf(vc[2 * 64 + 32 + lq]); vf[3] = f2bf(vc[3 * 64 + 32 + lq]); \
        o2 = MFMA(vf, pf, o2); \
        vf[0] = f2bf(vc[0 * 64 + 48 + lq]); vf[1] = f2bf(vc[1 * 64 + 48 + lq]); \
        vf[2] = f2bf(vc[2 * 64 + 48 + lq]); vf[3] = f2bf(vc[3 * 64 + 48 + lq]); \
        o3 = MFMA(vf, pf, o3); \
    } while (0)

    float4 kA0, kA1, kA2, kA3, kB0, kB1, kB2, kB3;
    ISSUE_K(0, kA0, kA1, kA2, kA3);
    STAGE(0, lds_v[0]);

    #pragma unroll 1
    for (int tt = 0; tt < 8; ++tt) {
        // even tile t = 2*tt : prefetch t+1 (K->kB, V->buf1), compute from kA/buf0
        ISSUE_K(2 * tt + 1, kB0, kB1, kB2, kB3);
        STAGE(2 * tt + 1, lds_v[1]);
        COMPUTE(kA0, kA1, kA2, kA3, 0);
        // odd tile t = 2*tt+1 : prefetch t+1 (K->kA, V->buf0), compute from kB/buf1
        if (tt < 7) {
            ISSUE_K(2 * tt + 2, kA0, kA1, kA2, kA3);
            STAGE(2 * tt + 2, lds_v[0]);
        }
        COMPUTE(kB0, kB1, kB2, kB3, 1);
    }
    #undef COMPUTE
    #undef STAGE
    #undef ISSUE_K

    // ---- the 16 new tokens (wave 0 of split-0 block) ----
    if (split == 0 && wave == 0) {
        const float* kr = knew + (size_t)(b * NS + lq) * HID + h * HD + g * 8;
        float4 ka = *reinterpret_cast<const float4*>(kr);
        float4 kb2 = *reinterpret_cast<const float4*>(kr + 4);
        float4 kc2 = *reinterpret_cast<const float4*>(kr + 32);
        float4 kd2 = *reinterpret_cast<const float4*>(kr + 36);
        short8 af0 = pack8(ka, kb2);
        short8 af1 = pack8(kc2, kd2);
        f32x4 sv = {0.f, 0.f, 0.f, 0.f};
        sv = MFMA(af0, qf0, sv);
        sv = MFMA(af1, qf1, sv);

        float tmax = fmaxf(fmaxf(sv[0], sv[1]), fmaxf(sv[2], sv[3]));
        tmax = fmaxf(tmax, __shfl_xor(tmax, 16));
        tmax = fmaxf(tmax, __shfl_xor(tmax, 32));
        float mn = fmaxf(m, tmax);
        float alpha = exp2f(m - mn);
        float e0 = exp2f(sv[0] - mn);
        float e1 = exp2f(sv[1] - mn);
        float e2 = exp2f(sv[2] - mn);
        float e3 = exp2f(sv[3] - mn);
        float rsum = e0 + e1 + e2 + e3;
        rsum += __shfl_xor(rsum, 16);
        rsum += __shfl_xor(rsum, 32);
        lsum = lsum * alpha + rsum;
        m = mn;
        o0 *= alpha; o1 *= alpha; o2 *= alpha; o3 *= alpha;

        short8 pfT;
        pfT[0] = f2bf(e0); pfT[1] = f2bf(e1); pfT[2] = f2bf(e2); pfT[3] = f2bf(e3);
        pfT[4] = 0; pfT[5] = 0; pfT[6] = 0; pfT[7] = 0;

        const float* vt2 = vnew + (size_t)(b * NS) * HID + h * HD;
        #define LOADVT(dst, dcol) do { \
            dst[0] = f2bf(vt2[(size_t)((g << 2) + 0) * HID + (dcol)]); \
            dst[1] = f2bf(vt2[(size_t)((g << 2) + 1) * HID + (dcol)]); \
            dst[2] = f2bf(vt2[(size_t)((g << 2) + 2) * HID + (dcol)]); \
            dst[3] = f2bf(vt2[(size_t)((g << 2) + 3) * HID + (dcol)]); \
            dst[4] = 0; dst[5] = 0; dst[6] = 0; dst[7] = 0; \
        } while (0)
        short8 vv0, vv1, vv2, vv3;
        LOADVT(vv0, lq); LOADVT(vv1, 16 + lq); LOADVT(vv2, 32 + lq); LOADVT(vv3, 48 + lq);
        #undef LOADVT
        o0 = MFMA(vv0, pfT, o0);
        o1 = MFMA(vv1, pfT, o1);
        o2 = MFMA(vv2, pfT, o2);
        o3 = MFMA(vv3, pfT, o3);
    }

    // ---- merge the 4 wave-partials; s_o unions lds_v (reads long drained) ----
    float* so_w = (float*)lds_v[0] + wave * 1024;   // [16 q][64 d] per wave
    #define STO(ov, dt) do { \
        so_w[lq * 64 + (dt) * 16 + (g << 2) + 0] = ov[0]; \
        so_w[lq * 64 + (dt) * 16 + (g << 2) + 1] = ov[1]; \
        so_w[lq * 64 + (dt) * 16 + (g << 2) + 2] = ov[2]; \
        so_w[lq * 64 + (dt) * 16 + (g << 2) + 3] = ov[3]; \
    } while (0)
    STO(o0, 0); STO(o1, 1); STO(o2, 2); STO(o3, 3);
    #undef STO
    if (g == 0) { s_m[wave][lq] = m; s_l[wave][lq] = lsum; }
    __syncthreads();

    if (wave == 0) {
        float M = fmaxf(fmaxf(s_m[0][lq], s_m[1][lq]), fmaxf(s_m[2][lq], s_m[3][lq]));
        float aw0 = exp2f(s_m[0][lq] - M);
        float aw1 = exp2f(s_m[1][lq] - M);
        float aw2 = exp2f(s_m[2][lq] - M);
        float aw3 = exp2f(s_m[3][lq] - M);
        float L = aw0 * s_l[0][lq] + aw1 * s_l[1][lq] + aw2 * s_l[2][lq] + aw3 * s_l[3][lq];
        const float* so0 = (const float*)lds_v[0] + 0 * 1024;
        const float* so1 = (const float*)lds_v[0] + 1 * 1024;
        const float* so2 = (const float*)lds_v[0] + 2 * 1024;
        const float* so3 = (const float*)lds_v[0] + 3 * 1024;
        float* pbase = parts + (size_t)bid * PART_STRIDE;
        if (g == 0) { pbase[lq] = M; pbase[16 + lq] = L; }
        for (int dd = 0; dd < 16; ++dd) {
            int di = g * 16 + dd;
            float v = aw0 * so0[lq * 64 + di] + aw1 * so1[lq * 64 + di] +
                      aw2 * so2[lq * 64 + di] + aw3 * so3[lq * 64 + di];
            pbase[32 + lq * 64 + di] = v;
        }
    }
}

// ---------------- merge the 4 split-partials per (b,h) -------------------
__global__ __launch_bounds__(256) void merge_kernel(const float* __restrict__ parts,
                                                    short* __restrict__ attnb) {
    int bh = blockIdx.x;            // b*32 + h
    int tid = threadIdx.x;
    int qi = tid >> 4, ds = (tid & 15) * 4;
    const float* p0 = parts + (size_t)(bh * NSPLIT) * PART_STRIDE;
    const float* p1 = p0 + PART_STRIDE;
    const float* p2 = p1 + PART_STRIDE;
    const float* p3 = p2 + PART_STRIDE;
    float m0 = p0[qi], m1 = p1[qi], m2 = p2[qi], m3 = p3[qi];
    float M = fmaxf(fmaxf(m0, m1), fmaxf(m2, m3));
    float a0 = exp2f(m0 - M), a1 = exp2f(m1 - M), a2 = exp2f(m2 - M), a3 = exp2f(m3 - M);
    float inv = 1.0f / (a0 * p0[16 + qi] + a1 * p1[16 + qi] +
                        a2 * p2[16 + qi] + a3 * p3[16 + qi]);
    int b = bh >> 5, h = bh & 31;
    int base = 32 + qi * 64 + ds;
    float v0 = (a0 * p0[base + 0] + a1 * p1[base + 0] + a2 * p2[base + 0] + a3 * p3[base + 0]) * inv;
    float v1 = (a0 * p0[base + 1] + a1 * p1[base + 1] + a2 * p2[base + 1] + a3 * p3[base + 1]) * inv;
    float v2 = (a0 * p0[base + 2] + a1 * p1[base + 2] + a2 * p2[base + 2] + a3 * p3[base + 2]) * inv;
    float v3 = (a0 * p0[base + 3] + a1 * p1[base + 3] + a2 * p2[base + 3] + a3 * p3[base + 3]) * inv;
    short4v o;
    o[0] = f2bf(v0); o[1] = f2bf(v1); o[2] = f2bf(v2); o[3] = f2bf(v3);
    *reinterpret_cast<short4v*>(attnb + (size_t)(b * NS + qi) * HID + h * HD + ds) = o;
}

extern "C" void kernel_launch(void* const* d_in, const int* in_sizes, int n_in,
                              void* d_out, int out_size, void* d_ws, size_t ws_size,
                              hipStream_t stream) {
    const float* hs     = (const float*)d_in[0];
    const float* past_k = (const float*)d_in[1];
    const float* past_v = (const float*)d_in[2];
    const float* wq     = (const float*)d_in[3];
    const float* wk     = (const float*)d_in[4];
    const float* wv     = (const float*)d_in[5];
    const float* wo     = (const float*)d_in[6];
    float* out = (float*)d_out;

    float* qb    = (float*)d_ws;                  // 128x2048 f32
    float* kn    = qb + MATSZ;                    // 128x2048 f32
    float* vn    = kn + MATSZ;                    // 128x2048 f32
    short* hsb   = (short*)(vn + MATSZ);          // 128x2048 bf16
    short* attnb = hsb + MATSZ;                   // 128x2048 bf16
    float* parts = (float*)(attnb + MATSZ);       // 1024 * PART_STRIDE f32
    float* qkvp  = parts + 1024 * PART_STRIDE;    // 3*4*MATSZ f32 partials
    float* op    = qkvp + 3 * 4 * MATSZ;          // 4*MATSZ f32 partials

    cvt_kernel<<<256, 256, 0, stream>>>(hs, hsb);
    proj_kernel<<<1536, 128, 0, stream>>>(hsb, wq, wk, wv, qkvp);
    merge4_kernel<<<768, 256, 0, stream>>>(qkvp, qb, kn, vn);
    attn_kernel<<<256 * NSPLIT, 256, 0, stream>>>(qb, kn, vn, past_k, past_v, parts);
    merge_kernel<<<256, 256, 0, stream>>>(parts, attnb);
    proj_kernel<<<512, 128, 0, stream>>>(attnb, wo, wo, wo, op);
    merge4_kernel<<<256, 256, 0, stream>>>(op, out, out, out);
}